// Round 2
// baseline (85.135 us; speedup 1.0000x reference)
//
#include <hip/hip_runtime.h>
#include <math.h>

// Problem dims (fixed by setup_inputs)
#define NROWS 8192   // B*T = 4*2048
#define DD    1024
#define HH    256
#define NTT   32
#define NCOLS 288    // HH + NTT

typedef __attribute__((ext_vector_type(8))) __bf16 bf16x8;
typedef __attribute__((ext_vector_type(4))) float f32x4;
typedef __attribute__((ext_vector_type(8))) unsigned short ushort8_t;

static __device__ __forceinline__ unsigned short f2bf(float f) {
    unsigned int u = __float_as_uint(f);
    unsigned int r = (u + 0x7fffu + ((u >> 16) & 1u)) >> 16;
    return (unsigned short)r;
}

static __device__ __forceinline__ float sgnf(float x) {
    return x > 0.0f ? 1.0f : (x < 0.0f ? -1.0f : 0.0f);
}

static __device__ __forceinline__ float ternf(float x) {
    return x > 0.3f ? 1.0f : (x < -0.3f ? -1.0f : 0.0f);
}

static __device__ __forceinline__ float bspline(float u) {
    float t = fabsf(u);
    if (t < 1.0f) return 0.66666666666666663f - t * t + 0.5f * t * t * t;
    if (t < 2.0f) { float w = 2.0f - t; return 0.16666666666666666f * w * w * w; }
    return 0.0f;
}

// ---------------- K0a: WT rows 0..255 = gamma-folded W1^T (bf16) ----------------
// WT[j][d] = gamma[d] * W1[d][j]
__global__ __launch_bounds__(256) void k_prep_w1t(const float* __restrict__ W1,
                                                  const float* __restrict__ gamma,
                                                  unsigned short* __restrict__ WT) {
    __shared__ float tile[32][33];
    int ktile = blockIdx.x;           // 0..31 (d tiles of 32)
    int ntile = blockIdx.y;           // 0..7  (j tiles of 32)
    int tx = threadIdx.x & 31;
    int ty = threadIdx.x >> 5;        // 0..7
#pragma unroll
    for (int i = 0; i < 4; ++i) {
        int k = ktile * 32 + ty + i * 8;
        int n = ntile * 32 + tx;
        tile[ty + i * 8][tx] = W1[(size_t)k * HH + n] * gamma[k];   // coalesced over n
    }
    __syncthreads();
#pragma unroll
    for (int i = 0; i < 4; ++i) {
        int n = ntile * 32 + ty + i * 8;
        int k = ktile * 32 + tx;
        WT[(size_t)n * DD + k] = f2bf(tile[tx][ty + i * 8]);  // coalesced over k
    }
}

// ---------------- K0b: WT rows 256..287 = gamma * sign(directions); + corr sums ----
// One block per tile row r. Also writes colsum[256+r] = sum_d g_d*s_rd,
// bw[256+r] = sum_d beta_d*s_rd.
__global__ __launch_bounds__(256) void k_prep_sig(const float* __restrict__ dirs,
                                                  const float* __restrict__ gamma,
                                                  const float* __restrict__ beta,
                                                  unsigned short* __restrict__ WT,
                                                  float* __restrict__ colsum,
                                                  float* __restrict__ bwv) {
    int r = blockIdx.x;               // 0..31
    int tid = threadIdx.x;
    float4 v  = ((const float4*)(dirs + (size_t)r * DD))[tid];
    float4 g  = ((const float4*)gamma)[tid];
    float4 be = ((const float4*)beta)[tid];
    float s0 = sgnf(v.x), s1 = sgnf(v.y), s2 = sgnf(v.z), s3 = sgnf(v.w);
    ushort4 o;
    o.x = f2bf(s0 * g.x); o.y = f2bf(s1 * g.y);
    o.z = f2bf(s2 * g.z); o.w = f2bf(s3 * g.w);
    ((ushort4*)(WT + (size_t)(HH + r) * DD))[tid] = o;
    float ps = s0 * g.x + s1 * g.y + s2 * g.z + s3 * g.w;
    float pb = s0 * be.x + s1 * be.y + s2 * be.z + s3 * be.w;
#pragma unroll
    for (int off = 32; off; off >>= 1) {
        ps += __shfl_xor(ps, off);
        pb += __shfl_xor(pb, off);
    }
    __shared__ float red[8];
    int wid = tid >> 6, lane = tid & 63;
    if (lane == 0) { red[wid] = ps; red[wid + 4] = pb; }
    __syncthreads();
    if (tid == 0) {
        colsum[HH + r] = red[0] + red[1] + red[2] + red[3];
        bwv[HH + r]    = red[4] + red[5] + red[6] + red[7];
    }
}

// ---------------- K0c: corr sums for j<256 ----------------
// colsum[j] = sum_d gamma[d]*W1[d][j], bw[j] = sum_d beta[d]*W1[d][j]
__global__ __launch_bounds__(256) void k_corr_w1(const float* __restrict__ W1,
                                                 const float* __restrict__ gamma,
                                                 const float* __restrict__ beta,
                                                 float* __restrict__ colsum,
                                                 float* __restrict__ bwv) {
    int b = blockIdx.x;               // 0..7
    int tx = threadIdx.x & 31;
    int ty = threadIdx.x >> 5;        // 0..7
    int j = b * 32 + tx;
    float sg = 0.f, sb = 0.f;
    for (int d = ty; d < DD; d += 8) {
        float w = W1[(size_t)d * HH + j];
        sg += gamma[d] * w;
        sb += beta[d] * w;
    }
    __shared__ float red[2][8][32];
    red[0][ty][tx] = sg;
    red[1][ty][tx] = sb;
    __syncthreads();
    if (ty == 0) {
        float a = 0.f, c = 0.f;
#pragma unroll
        for (int k = 0; k < 8; ++k) { a += red[0][k][tx]; c += red[1][k][tx]; }
        colsum[j] = a;
        bwv[j] = c;
    }
}

// ---------------- K2: fused LN-GEMM ----------------
// HP[row][j] = rstd*( x_row @ WT_j ) - mu*rstd*colsum[j] + bw[j]
// A = bf16(x) reg-staged (f32 load -> cvt -> swizzled ds_write); stats (mu,rstd)
// computed in-kernel from the same staged registers.
// BM=64, BN=96, BK=64; 4 waves (2Mx2N); wave tile 32x48 (Mf=2, Nf=3).
// LDS row stride 128B, XOR swizzle byte ^= ((row&7)<<4) on write AND read.
__global__ __launch_bounds__(256) void k_gemm(const float* __restrict__ x,
                                              const unsigned short* __restrict__ WT,
                                              const float* __restrict__ colsum,
                                              const float* __restrict__ bwv,
                                              float* __restrict__ HP) {
    __shared__ short Al[64 * 64];    // 8KB
    __shared__ short Bl[96 * 64];    // 12KB
    __shared__ float stats[64][2];
    int tid = threadIdx.x;
    int colblk = blockIdx.x;         // 0..2
    int rowblk = blockIdx.y;         // 0..127
    int row0  = rowblk * 64;
    int ncol0 = colblk * 96;
    int lane = tid & 63;
    int wid  = tid >> 6;
    int wm = wid >> 1, wn = wid & 1;
    int l15 = lane & 15, l4 = lane >> 4;

    // A staging map: 4 threads per row, 16 cols (4xfloat4) each
    int rA = tid >> 2;               // 0..63
    int cA = (tid & 3) * 16;         // element col base
    const float* xrow = x + (size_t)(row0 + rA) * DD + cA;
    int abase = rA * 128 + cA * 2;   // LDS byte base (unswizzled)
    int aswz  = (rA & 7) << 4;

    float s = 0.f, sq = 0.f;
    f32x4 acc[2][3];
#pragma unroll
    for (int i = 0; i < 2; ++i)
#pragma unroll
        for (int j = 0; j < 3; ++j) acc[i][j] = (f32x4){0.f, 0.f, 0.f, 0.f};

    for (int kt = 0; kt < 16; ++kt) {
        // stage B: 96x64 bf16 = 12KB = 3 issues of 256 lanes x 16B
#pragma unroll
        for (int ci = 0; ci < 3; ++ci) {
            int li = ci * 256 + tid;
            int r  = li >> 3;
            int g  = li & 7;
            int scol = (g * 8) ^ ((r & 7) << 3);
            const unsigned short* src = WT + (size_t)(ncol0 + r) * DD + kt * 64 + scol;
            __builtin_amdgcn_global_load_lds(
                (const __attribute__((address_space(1))) void*)(const void*)src,
                (__attribute__((address_space(3))) void*)(void*)(Bl + li * 8), 16, 0, 0);
        }
        // stage A: load 16 f32, accumulate stats, cvt to bf16, swizzled ds_write
        float4 v0 = ((const float4*)(xrow + kt * 64))[0];
        float4 v1 = ((const float4*)(xrow + kt * 64))[1];
        float4 v2 = ((const float4*)(xrow + kt * 64))[2];
        float4 v3 = ((const float4*)(xrow + kt * 64))[3];
        s  += (v0.x + v0.y + v0.z + v0.w) + (v1.x + v1.y + v1.z + v1.w)
            + (v2.x + v2.y + v2.z + v2.w) + (v3.x + v3.y + v3.z + v3.w);
        sq += (v0.x*v0.x + v0.y*v0.y + v0.z*v0.z + v0.w*v0.w)
            + (v1.x*v1.x + v1.y*v1.y + v1.z*v1.z + v1.w*v1.w)
            + (v2.x*v2.x + v2.y*v2.y + v2.z*v2.z + v2.w*v2.w)
            + (v3.x*v3.x + v3.y*v3.y + v3.z*v3.z + v3.w*v3.w);
        ushort8_t w0, w1;
        w0[0] = f2bf(v0.x); w0[1] = f2bf(v0.y); w0[2] = f2bf(v0.z); w0[3] = f2bf(v0.w);
        w0[4] = f2bf(v1.x); w0[5] = f2bf(v1.y); w0[6] = f2bf(v1.z); w0[7] = f2bf(v1.w);
        w1[0] = f2bf(v2.x); w1[1] = f2bf(v2.y); w1[2] = f2bf(v2.z); w1[3] = f2bf(v2.w);
        w1[4] = f2bf(v3.x); w1[5] = f2bf(v3.y); w1[6] = f2bf(v3.z); w1[7] = f2bf(v3.w);
        *(ushort8_t*)((char*)Al + ((abase)      ^ aswz)) = w0;
        *(ushort8_t*)((char*)Al + ((abase + 16) ^ aswz)) = w1;
        __syncthreads();

#pragma unroll
        for (int ks = 0; ks < 2; ++ks) {
            bf16x8 avf[2], bvf[3];
#pragma unroll
            for (int mf = 0; mf < 2; ++mf) {
                int r = wm * 32 + mf * 16 + l15;
                int cb = (ks * 64 + l4 * 16) ^ ((r & 7) << 4);
                avf[mf] = *(const bf16x8*)((const char*)Al + r * 128 + cb);
            }
#pragma unroll
            for (int nf = 0; nf < 3; ++nf) {
                int r = wn * 48 + nf * 16 + l15;
                int cb = (ks * 64 + l4 * 16) ^ ((r & 7) << 4);
                bvf[nf] = *(const bf16x8*)((const char*)Bl + r * 128 + cb);
            }
#pragma unroll
            for (int mf = 0; mf < 2; ++mf)
#pragma unroll
                for (int nf = 0; nf < 3; ++nf)
                    acc[mf][nf] = __builtin_amdgcn_mfma_f32_16x16x32_bf16(
                        avf[mf], bvf[nf], acc[mf][nf], 0, 0, 0);
        }
        __syncthreads();
    }

    // finalize stats: reduce across the 4 staging threads of each row
    s  += __shfl_xor(s, 1);  s  += __shfl_xor(s, 2);
    sq += __shfl_xor(sq, 1); sq += __shfl_xor(sq, 2);
    if ((tid & 3) == 0) {
        float mu  = s * (1.0f / DD);
        float var = sq * (1.0f / DD) - mu * mu;
        stats[rA][0] = mu;
        stats[rA][1] = rsqrtf(var + 1e-5f);
    }
    __syncthreads();

    // corrected write: D frag layout col=lane&15, row=(lane>>4)*4+i
#pragma unroll
    for (int mf = 0; mf < 2; ++mf) {
#pragma unroll
        for (int nf = 0; nf < 3; ++nf) {
            int colg = ncol0 + wn * 48 + nf * 16 + l15;
            float cs = colsum[colg];
            float bw = bwv[colg];
            int rl0 = wm * 32 + mf * 16 + l4 * 4;
#pragma unroll
            for (int i = 0; i < 4; ++i) {
                float mu   = stats[rl0 + i][0];
                float rstd = stats[rl0 + i][1];
                HP[(size_t)(row0 + rl0 + i) * NCOLS + colg] =
                    rstd * acc[mf][nf][i] - mu * rstd * cs + bw;
            }
        }
    }
}

// ---------------- K3: per-row epilogue + output ----------------
// 1 wave per row; block = 4 rows.
__global__ __launch_bounds__(256) void k_epilogue(
    const float* __restrict__ HP, const float* __restrict__ x,
    const float* __restrict__ positions, const int* __restrict__ states,
    const float* __restrict__ b1, const float* __restrict__ W2,
    const float* __restrict__ b2, const float* __restrict__ spc,
    const float* __restrict__ sps, const float* __restrict__ dirs,
    const float* __restrict__ ssig, const float* __restrict__ semb,
    const float* __restrict__ smod, const float* __restrict__ oscale,
    float* __restrict__ out) {
    int wid = threadIdx.x >> 6;
    int lane = threadIdx.x & 63;
    int row = blockIdx.x * 4 + wid;

    const float* hrow = HP + (size_t)row * NCOLS;
    float4 hv  = ((const float4*)hrow)[lane];          // h_pre[lane*4 .. +3]
    float4 b1v = ((const float4*)b1)[lane];
    float hs[4] = {hv.x, hv.y, hv.z, hv.w};
    float bs[4] = {b1v.x, b1v.y, b1v.z, b1v.w};
    float sa = 0.f, sb = 0.f;
#pragma unroll
    for (int i = 0; i < 4; ++i) {
        float h = hs[i] + bs[i];
        float g = 0.5f * h * (1.0f + erff(h * 0.70710678118654752f));  // exact gelu
        int j = lane * 4 + i;
        sa += g * W2[2 * j];
        sb += g * W2[2 * j + 1];
    }
#pragma unroll
    for (int off = 32; off; off >>= 1) {
        sa += __shfl_xor(sa, off);
        sb += __shfl_xor(sb, off);
    }
    float av = tanhf(sa + b2[0]);
    float bv = tanhf(sb + b2[1]);

    int st = states[row];
    float comb;
    if (lane < NTT) {
        float content = hrow[HH + lane];
        float pn = positions[row] * ((float)NTT / 2048.0f);
        float u  = (pn - (float)lane) * 0.5f;            // /SPREAD
        float spv = bspline(u);
        const float* sg = ssig + lane * 8;
        const float* se = semb + st * 8;
        float d0 = 0.f;
#pragma unroll
        for (int k = 0; k < 8; ++k) d0 += se[k] * sg[k];
        float temporal = 1.0f / (1.0f + expf(-d0));
        comb = content * spv * temporal;
    } else {
        comb = -__builtin_inff();
    }
    int bi = lane;
#pragma unroll
    for (int off = 32; off; off >>= 1) {
        float ov = __shfl_xor(comb, off);
        int   oi = __shfl_xor(bi, off);
        if (ov > comb || (ov == comb && oi < bi)) { comb = ov; bi = oi; }
    }
    int ia = (int)((av + 1.0f) / 2.0f * 16.0f); ia = ia < 0 ? 0 : (ia > 15 ? 15 : ia);
    int ib = (int)((bv + 1.0f) / 2.0f * 16.0f); ib = ib < 0 ? 0 : (ib > 15 ? 15 : ib);
    const float* cc = spc + (((size_t)bi * 16 + ia) * 16 + ib) * 3;
    float c0 = ternf(cc[0]), c1 = ternf(cc[1]), c2 = ternf(cc[2]);
    const float csz = 0.125f;
    float la = (av + 1.0f - (float)ia * csz) * 8.0f;     // /cs
    float lb = (bv + 1.0f - (float)ib * csz) * 8.0f;
    float scale = (c0 + c1 * la + c2 * lb) * sps[bi];
    float sm = smod[st * NTT + bi];
    float cr = scale * sm * oscale[0];

    const float4* xr = (const float4*)(x + (size_t)row * DD);
    const float4* dr = (const float4*)(dirs + (size_t)bi * DD);
    float4* orow = (float4*)(out + (size_t)row * DD);
#pragma unroll
    for (int i = 0; i < 4; ++i) {
        int idx = i * 64 + lane;
        float4 xv = xr[idx];
        float4 dv = dr[idx];
        float4 o;
        o.x = fmaf(cr, dv.x, xv.x);
        o.y = fmaf(cr, dv.y, xv.y);
        o.z = fmaf(cr, dv.z, xv.z);
        o.w = fmaf(cr, dv.w, xv.w);
        orow[idx] = o;
    }
}

extern "C" void kernel_launch(void* const* d_in, const int* in_sizes, int n_in,
                              void* d_out, int out_size, void* d_ws, size_t ws_size,
                              hipStream_t stream) {
    const float* x     = (const float*)d_in[0];
    const float* pos   = (const float*)d_in[1];
    const int*   st    = (const int*)d_in[2];
    const float* gam   = (const float*)d_in[3];
    const float* bet   = (const float*)d_in[4];
    const float* W1    = (const float*)d_in[5];
    const float* b1    = (const float*)d_in[6];
    const float* W2    = (const float*)d_in[7];
    const float* b2    = (const float*)d_in[8];
    const float* spc   = (const float*)d_in[9];
    const float* sps   = (const float*)d_in[10];
    const float* dirs  = (const float*)d_in[11];
    const float* ssig  = (const float*)d_in[12];
    const float* semb  = (const float*)d_in[13];
    const float* smod  = (const float*)d_in[14];
    const float* oscal = (const float*)d_in[15];
    float* out = (float*)d_out;

    char* ws = (char*)d_ws;
    unsigned short* WT = (unsigned short*)ws;                  // 288*1024 bf16 = 576 KiB
    float* HP     = (float*)(ws + 589824);                     // 8192*288 f32 = 9 MiB
    float* colsum = (float*)(ws + 10027008);                   // 288 f32
    float* bwv    = (float*)(ws + 10028160);                   // 288 f32

    k_prep_w1t<<<dim3(32, 8), 256, 0, stream>>>(W1, gam, WT);
    k_prep_sig<<<32, 256, 0, stream>>>(dirs, gam, bet, WT, colsum, bwv);
    k_corr_w1<<<8, 256, 0, stream>>>(W1, gam, bet, colsum, bwv);
    k_gemm<<<dim3(3, 128), 256, 0, stream>>>(x, WT, colsum, bwv, HP);
    k_epilogue<<<NROWS / 4, 256, 0, stream>>>(HP, x, pos, st, b1, W2, b2, spc, sps,
                                              dirs, ssig, semb, smod, oscal, out);
}

// Round 3
// 42.326 us; speedup vs baseline: 2.0114x; 2.0114x over previous
//
#include <hip/hip_runtime.h>
#include <math.h>

// Problem dims (fixed by setup_inputs)
#define NROWS 8192   // B*T = 4*2048
#define DD    1024
#define HH    256
#define NTT   32
#define NCOLS 288    // HH + NTT
#define BM    32
#define BK    64
#define NW    12     // waves in fused kernel (768 threads)
#define HPS   292    // HP LDS row stride (floats), padded to spread banks

typedef __attribute__((ext_vector_type(8))) __bf16 bf16x8;
typedef __attribute__((ext_vector_type(4))) float f32x4;
typedef __attribute__((ext_vector_type(8))) unsigned short ushort8_t;

static __device__ __forceinline__ unsigned short f2bf(float f) {
    unsigned int u = __float_as_uint(f);
    unsigned int r = (u + 0x7fffu + ((u >> 16) & 1u)) >> 16;
    return (unsigned short)r;
}

static __device__ __forceinline__ float sgnf(float x) {
    return x > 0.0f ? 1.0f : (x < 0.0f ? -1.0f : 0.0f);
}

static __device__ __forceinline__ float ternf(float x) {
    return x > 0.3f ? 1.0f : (x < -0.3f ? -1.0f : 0.0f);
}

static __device__ __forceinline__ float bspline(float u) {
    float t = fabsf(u);
    if (t < 1.0f) return 0.66666666666666663f - t * t + 0.5f * t * t * t;
    if (t < 2.0f) { float w = 2.0f - t; return 0.16666666666666666f * w * w * w; }
    return 0.0f;
}

// ---------------- K0a: k_prep_sig (runs FIRST) ----------------
// Zeros colsum/bw [0..255]; writes WT rows 256..287 = gamma*sign(dirs);
// writes colsum/bw [256+r] directly.
__global__ __launch_bounds__(256) void k_prep_sig(const float* __restrict__ dirs,
                                                  const float* __restrict__ gamma,
                                                  const float* __restrict__ beta,
                                                  unsigned short* __restrict__ WT,
                                                  float* __restrict__ colsum,
                                                  float* __restrict__ bwv) {
    int r = blockIdx.x;               // 0..31
    int tid = threadIdx.x;
    if (tid < 8) {                    // zero the j<256 slots for the atomic pass
        colsum[r * 8 + tid] = 0.0f;
        bwv[r * 8 + tid]    = 0.0f;
    }
    float4 v  = ((const float4*)(dirs + (size_t)r * DD))[tid];
    float4 g  = ((const float4*)gamma)[tid];
    float4 be = ((const float4*)beta)[tid];
    float s0 = sgnf(v.x), s1 = sgnf(v.y), s2 = sgnf(v.z), s3 = sgnf(v.w);
    ushort4 o;
    o.x = f2bf(s0 * g.x); o.y = f2bf(s1 * g.y);
    o.z = f2bf(s2 * g.z); o.w = f2bf(s3 * g.w);
    ((ushort4*)(WT + (size_t)(HH + r) * DD))[tid] = o;
    float ps = s0 * g.x + s1 * g.y + s2 * g.z + s3 * g.w;
    float pb = s0 * be.x + s1 * be.y + s2 * be.z + s3 * be.w;
#pragma unroll
    for (int off = 32; off; off >>= 1) {
        ps += __shfl_xor(ps, off);
        pb += __shfl_xor(pb, off);
    }
    __shared__ float red[8];
    int wid = tid >> 6, lane = tid & 63;
    if (lane == 0) { red[wid] = ps; red[wid + 4] = pb; }
    __syncthreads();
    if (tid == 0) {
        colsum[HH + r] = red[0] + red[1] + red[2] + red[3];
        bwv[HH + r]    = red[4] + red[5] + red[6] + red[7];
    }
}

// ---------------- K0b: k_prep_w1t ----------------
// WT[j][d] = gamma[d]*W1[d][j] (bf16 transpose) + atomic partial colsum/bw.
__global__ __launch_bounds__(256) void k_prep_w1t(const float* __restrict__ W1,
                                                  const float* __restrict__ gamma,
                                                  const float* __restrict__ beta,
                                                  unsigned short* __restrict__ WT,
                                                  float* __restrict__ colsum,
                                                  float* __restrict__ bwv) {
    __shared__ float tile[32][33];
    __shared__ float redg[8][32];
    __shared__ float redb[8][32];
    int ktile = blockIdx.x;           // 0..31 (d tiles of 32)
    int ntile = blockIdx.y;           // 0..7  (j tiles of 32)
    int tx = threadIdx.x & 31;
    int ty = threadIdx.x >> 5;        // 0..7
    float sg = 0.f, sb = 0.f;
#pragma unroll
    for (int i = 0; i < 4; ++i) {
        int k = ktile * 32 + ty + i * 8;
        int n = ntile * 32 + tx;
        float w = W1[(size_t)k * HH + n];           // coalesced over n
        float gk = gamma[k];
        tile[ty + i * 8][tx] = w * gk;
        sg += w * gk;
        sb += w * beta[k];
    }
    redg[ty][tx] = sg;
    redb[ty][tx] = sb;
    __syncthreads();
#pragma unroll
    for (int i = 0; i < 4; ++i) {
        int n = ntile * 32 + ty + i * 8;
        int k = ktile * 32 + tx;
        WT[(size_t)n * DD + k] = f2bf(tile[tx][ty + i * 8]);  // coalesced over k
    }
    if (ty == 0) {
        float a = 0.f, c = 0.f;
#pragma unroll
        for (int k = 0; k < 8; ++k) { a += redg[k][tx]; c += redb[k][tx]; }
        int j = ntile * 32 + tx;
        atomicAdd(&colsum[j], a);
        atomicAdd(&bwv[j], c);
    }
}

// ---------------- K1: fully fused LN-GEMM + epilogue ----------------
// 256 blocks (1/CU), 768 threads (12 waves: 2M x 6N), BM=32, BN=288, BK=64.
// Double-buffered LDS; A reg-staged (f32->bf16, swizzled ds_write) with LN
// stats on the fly; B via global_load_lds (pre-swizzled source, rule 21).
// After K-loop: LN-corrected 32x288 tile -> LDS (aliases B), then per-row
// epilogue (gelu/W2/tanh/spline/argmax) and out = x + c*dirs[tile].
__global__ __launch_bounds__(768) void k_fused(
    const float* __restrict__ x, const unsigned short* __restrict__ WT,
    const float* __restrict__ colsum, const float* __restrict__ bwv,
    const float* __restrict__ positions, const int* __restrict__ states,
    const float* __restrict__ b1, const float* __restrict__ W2,
    const float* __restrict__ b2, const float* __restrict__ spc,
    const float* __restrict__ sps, const float* __restrict__ dirs,
    const float* __restrict__ ssig, const float* __restrict__ semb,
    const float* __restrict__ smod, const float* __restrict__ oscale,
    float* __restrict__ out) {
    __shared__ short Al[2][BM * BK];        // 2 x 4 KB
    __shared__ short Bl[2][NCOLS * BK];     // 2 x 36 KB
    __shared__ float stats[BM][2];
    float* HPl = (float*)&Bl[0][0];         // 32 x 292 f32 = 37376 B (aliases B)

    int tid  = threadIdx.x;
    int row0 = blockIdx.x * BM;
    int lane = tid & 63;
    int wid  = tid >> 6;                    // 0..11
    int wn = wid % 6, wm = wid / 6;
    int l15 = lane & 15, l4 = lane >> 4;

    // A staging ids (threads 0..255 = waves 0..3)
    int rA = tid >> 3;                      // 0..31
    int g8 = tid & 7;
    const float* xrow = x + (size_t)(row0 + rA) * DD + g8 * 8;
    int aoff = (rA * 128 + g8 * 16) ^ ((rA & 7) << 4);

    float s = 0.f, sq = 0.f;
    float4 va, vb;
    f32x4 acc[3];
#pragma unroll
    for (int nf = 0; nf < 3; ++nf) acc[nf] = (f32x4){0.f, 0.f, 0.f, 0.f};

#define STAGE_B(kt, buf)                                                         \
    {                                                                            \
        _Pragma("unroll")                                                        \
        for (int ci = 0; ci < 3; ++ci) {                                         \
            int li = ci * 768 + tid;                                             \
            int r  = li >> 3;                                                    \
            int g  = li & 7;                                                     \
            const unsigned short* src =                                          \
                WT + (size_t)r * DD + (kt) * 64 + ((g * 8) ^ ((r & 7) << 3));    \
            __builtin_amdgcn_global_load_lds(                                    \
                (const __attribute__((address_space(1))) void*)(const void*)src, \
                (__attribute__((address_space(3))) void*)(void*)(Bl[buf] + li * 8), \
                16, 0, 0);                                                       \
        }                                                                        \
    }

#define LOAD_A(kt)                                                \
    if (wid < 4) {                                                \
        va = ((const float4*)(xrow + (kt) * 64))[0];              \
        vb = ((const float4*)(xrow + (kt) * 64))[1];              \
    }

#define WRITE_A(buf)                                                        \
    if (wid < 4) {                                                          \
        s  += (va.x + va.y + va.z + va.w) + (vb.x + vb.y + vb.z + vb.w);    \
        sq += (va.x*va.x + va.y*va.y + va.z*va.z + va.w*va.w)               \
            + (vb.x*vb.x + vb.y*vb.y + vb.z*vb.z + vb.w*vb.w);              \
        ushort8_t w;                                                        \
        w[0] = f2bf(va.x); w[1] = f2bf(va.y); w[2] = f2bf(va.z); w[3] = f2bf(va.w); \
        w[4] = f2bf(vb.x); w[5] = f2bf(vb.y); w[6] = f2bf(vb.z); w[7] = f2bf(vb.w); \
        *(ushort8_t*)((char*)Al[buf] + aoff) = w;                           \
    }

    STAGE_B(0, 0);
    LOAD_A(0);
    WRITE_A(0);
    __syncthreads();

    for (int kt = 0; kt < 16; ++kt) {
        int cur = kt & 1, nxt = cur ^ 1;
        if (kt < 15) {
            STAGE_B(kt + 1, nxt);
            LOAD_A(kt + 1);
        }
#pragma unroll
        for (int ks = 0; ks < 2; ++ks) {
            int ra = wm * 16 + l15;
            int ca = (ks * 64 + l4 * 16) ^ ((ra & 7) << 4);
            bf16x8 av = *(const bf16x8*)((const char*)Al[cur] + ra * 128 + ca);
            bf16x8 bv[3];
#pragma unroll
            for (int nf = 0; nf < 3; ++nf) {
                int rb = wn * 48 + nf * 16 + l15;
                int cb = (ks * 64 + l4 * 16) ^ ((rb & 7) << 4);
                bv[nf] = *(const bf16x8*)((const char*)Bl[cur] + rb * 128 + cb);
            }
#pragma unroll
            for (int nf = 0; nf < 3; ++nf)
                acc[nf] = __builtin_amdgcn_mfma_f32_16x16x32_bf16(av, bv[nf], acc[nf], 0, 0, 0);
        }
        if (kt < 15) WRITE_A(nxt);
        __syncthreads();
    }

    // LN stats finalize (8 staging threads per row are adjacent lanes)
    if (wid < 4) {
        s  += __shfl_xor(s, 1);  s  += __shfl_xor(s, 2);  s  += __shfl_xor(s, 4);
        sq += __shfl_xor(sq, 1); sq += __shfl_xor(sq, 2); sq += __shfl_xor(sq, 4);
        if (g8 == 0) {
            float mu  = s * (1.0f / DD);
            float var = sq * (1.0f / DD) - mu * mu;
            stats[rA][0] = mu;
            stats[rA][1] = rsqrtf(var + 1e-5f);
        }
    }
    __syncthreads();

    // LN-corrected tile -> HPl (D frag: col=lane&15, row=(lane>>4)*4+i)
#pragma unroll
    for (int nf = 0; nf < 3; ++nf) {
        int colg = wn * 48 + nf * 16 + l15;
        float cs = colsum[colg];
        float bw = bwv[colg];
        int r0 = wm * 16 + l4 * 4;
#pragma unroll
        for (int i = 0; i < 4; ++i) {
            float mu = stats[r0 + i][0], rs = stats[r0 + i][1];
            HPl[(r0 + i) * HPS + colg] = rs * acc[nf][i] - mu * rs * cs + bw;
        }
    }
    __syncthreads();

    // ---- per-row epilogue; wave w handles rows w, w+12, w+24 ----
    float4 b1v = ((const float4*)b1)[lane];
    float w2a[4], w2b[4];
#pragma unroll
    for (int i = 0; i < 4; ++i) {
        int j = lane * 4 + i;
        w2a[i] = W2[2 * j];
        w2b[i] = W2[2 * j + 1];
    }
    float tvs[2] = {0.f, 0.f};
    if (lane < NTT) {
#pragma unroll
        for (int s2 = 0; s2 < 2; ++s2) {
            float d0 = 0.f;
#pragma unroll
            for (int k = 0; k < 8; ++k) d0 += semb[s2 * 8 + k] * ssig[lane * 8 + k];
            tvs[s2] = 1.0f / (1.0f + expf(-d0));
        }
    }
    float osc = oscale[0];
    float bb0 = b2[0], bb1 = b2[1];

    for (int r = wid; r < BM; r += NW) {
        int row = row0 + r;
        float4 hv = *(const float4*)&HPl[r * HPS + lane * 4];
        float hs[4] = {hv.x, hv.y, hv.z, hv.w};
        float bs[4] = {b1v.x, b1v.y, b1v.z, b1v.w};
        float sa = 0.f, sb2 = 0.f;
#pragma unroll
        for (int i = 0; i < 4; ++i) {
            float h = hs[i] + bs[i];
            float g = 0.5f * h * (1.0f + erff(h * 0.70710678118654752f));
            sa  += g * w2a[i];
            sb2 += g * w2b[i];
        }
#pragma unroll
        for (int off = 32; off; off >>= 1) {
            sa  += __shfl_xor(sa, off);
            sb2 += __shfl_xor(sb2, off);
        }
        float av2 = tanhf(sa + bb0);
        float bv2 = tanhf(sb2 + bb1);

        int st = states[row];
        float comb;
        if (lane < NTT) {
            float content = HPl[r * HPS + HH + lane];
            float pn = positions[row] * ((float)NTT / 2048.0f);
            float spv = bspline((pn - (float)lane) * 0.5f);
            comb = content * spv * tvs[st];
        } else {
            comb = -__builtin_inff();
        }
        int bi = lane;
#pragma unroll
        for (int off = 32; off; off >>= 1) {
            float ov = __shfl_xor(comb, off);
            int   oi = __shfl_xor(bi, off);
            if (ov > comb || (ov == comb && oi < bi)) { comb = ov; bi = oi; }
        }
        int ia = (int)((av2 + 1.0f) * 8.0f); ia = ia < 0 ? 0 : (ia > 15 ? 15 : ia);
        int ib = (int)((bv2 + 1.0f) * 8.0f); ib = ib < 0 ? 0 : (ib > 15 ? 15 : ib);
        const float* cc = spc + (((size_t)bi * 16 + ia) * 16 + ib) * 3;
        float c0 = ternf(cc[0]), c1 = ternf(cc[1]), c2 = ternf(cc[2]);
        float la = (av2 + 1.0f - (float)ia * 0.125f) * 8.0f;
        float lb = (bv2 + 1.0f - (float)ib * 0.125f) * 8.0f;
        float scale = (c0 + c1 * la + c2 * lb) * sps[bi];
        float cr = scale * smod[st * NTT + bi] * osc;

        const float4* xr = (const float4*)(x + (size_t)row * DD);
        const float4* dr = (const float4*)(dirs + (size_t)bi * DD);
        float4* orow = (float4*)(out + (size_t)row * DD);
#pragma unroll
        for (int i = 0; i < 4; ++i) {
            int idx = i * 64 + lane;
            float4 xv = xr[idx];
            float4 dv = dr[idx];
            float4 o;
            o.x = fmaf(cr, dv.x, xv.x);
            o.y = fmaf(cr, dv.y, xv.y);
            o.z = fmaf(cr, dv.z, xv.z);
            o.w = fmaf(cr, dv.w, xv.w);
            orow[idx] = o;
        }
    }
#undef STAGE_B
#undef LOAD_A
#undef WRITE_A
}

extern "C" void kernel_launch(void* const* d_in, const int* in_sizes, int n_in,
                              void* d_out, int out_size, void* d_ws, size_t ws_size,
                              hipStream_t stream) {
    const float* x     = (const float*)d_in[0];
    const float* pos   = (const float*)d_in[1];
    const int*   st    = (const int*)d_in[2];
    const float* gam   = (const float*)d_in[3];
    const float* bet   = (const float*)d_in[4];
    const float* W1    = (const float*)d_in[5];
    const float* b1    = (const float*)d_in[6];
    const float* W2    = (const float*)d_in[7];
    const float* b2    = (const float*)d_in[8];
    const float* spc   = (const float*)d_in[9];
    const float* sps   = (const float*)d_in[10];
    const float* dirs  = (const float*)d_in[11];
    const float* ssig  = (const float*)d_in[12];
    const float* semb  = (const float*)d_in[13];
    const float* smod  = (const float*)d_in[14];
    const float* oscal = (const float*)d_in[15];
    float* out = (float*)d_out;

    char* ws = (char*)d_ws;
    unsigned short* WT = (unsigned short*)ws;                  // 288*1024 bf16 = 576 KiB
    float* colsum = (float*)(ws + 589824);                     // 288 f32
    float* bwv    = (float*)(ws + 589824 + 1152);              // 288 f32

    k_prep_sig<<<32, 256, 0, stream>>>(dirs, gam, bet, WT, colsum, bwv);
    k_prep_w1t<<<dim3(32, 8), 256, 0, stream>>>(W1, gam, bet, WT, colsum, bwv);
    k_fused<<<NROWS / BM, 768, 0, stream>>>(x, WT, colsum, bwv, pos, st, b1, W2, b2,
                                            spc, sps, dirs, ssig, semb, smod, oscal, out);
}

// Round 4
// 41.807 us; speedup vs baseline: 2.0364x; 1.0124x over previous
//
#include <hip/hip_runtime.h>
#include <math.h>

// Problem dims (fixed by setup_inputs)
#define NROWS 8192   // B*T = 4*2048
#define DD    1024
#define HH    256
#define NTT   32
#define NCOLS 288    // HH + NTT
#define BM    32
#define BK    64
#define NW    12     // waves in fused kernel (768 threads)
#define HPS   292    // HP LDS row stride (floats), padded to spread banks

typedef __attribute__((ext_vector_type(8))) __bf16 bf16x8;
typedef __attribute__((ext_vector_type(4))) float f32x4;
typedef __attribute__((ext_vector_type(8))) unsigned short ushort8_t;

static __device__ __forceinline__ unsigned short f2bf(float f) {
    unsigned int u = __float_as_uint(f);
    unsigned int r = (u + 0x7fffu + ((u >> 16) & 1u)) >> 16;
    return (unsigned short)r;
}

static __device__ __forceinline__ float sgnf(float x) {
    return x > 0.0f ? 1.0f : (x < 0.0f ? -1.0f : 0.0f);
}

static __device__ __forceinline__ float ternf(float x) {
    return x > 0.3f ? 1.0f : (x < -0.3f ? -1.0f : 0.0f);
}

static __device__ __forceinline__ float bspline(float u) {
    float t = fabsf(u);
    if (t < 1.0f) return 0.66666666666666663f - t * t + 0.5f * t * t * t;
    if (t < 2.0f) { float w = 2.0f - t; return 0.16666666666666666f * w * w * w; }
    return 0.0f;
}

// ---------------- K0: merged prep (grid 288) ----------------
// blocks 0..255: WT[j][d] = gamma[d]*W1[d][j] (bf16 transpose) + atomic colsum/bw
// blocks 256..287: WT rows 256..287 = gamma*sign(dirs); direct colsum/bw writes.
// colsum/bw [0..255] zeroed beforehand via hipMemsetAsync.
__global__ __launch_bounds__(256) void k_prep(const float* __restrict__ W1,
                                              const float* __restrict__ dirs,
                                              const float* __restrict__ gamma,
                                              const float* __restrict__ beta,
                                              unsigned short* __restrict__ WT,
                                              float* __restrict__ colsum,
                                              float* __restrict__ bwv) {
    int bid = blockIdx.x;
    int tid = threadIdx.x;
    if (bid < 256) {
        __shared__ float tile[32][33];
        __shared__ float redg[8][32];
        __shared__ float redb[8][32];
        int ktile = bid & 31;            // d tiles of 32
        int ntile = bid >> 5;            // j tiles of 32
        int tx = tid & 31;
        int ty = tid >> 5;               // 0..7
        float sg = 0.f, sb = 0.f;
#pragma unroll
        for (int i = 0; i < 4; ++i) {
            int k = ktile * 32 + ty + i * 8;
            int n = ntile * 32 + tx;
            float w = W1[(size_t)k * HH + n];        // coalesced over n
            float gk = gamma[k];
            tile[ty + i * 8][tx] = w * gk;
            sg += w * gk;
            sb += w * beta[k];
        }
        redg[ty][tx] = sg;
        redb[ty][tx] = sb;
        __syncthreads();
#pragma unroll
        for (int i = 0; i < 4; ++i) {
            int n = ntile * 32 + ty + i * 8;
            int k = ktile * 32 + tx;
            WT[(size_t)n * DD + k] = f2bf(tile[tx][ty + i * 8]);  // coalesced over k
        }
        if (ty == 0) {
            float a = 0.f, c = 0.f;
#pragma unroll
            for (int k = 0; k < 8; ++k) { a += redg[k][tx]; c += redb[k][tx]; }
            int j = ntile * 32 + tx;
            atomicAdd(&colsum[j], a);
            atomicAdd(&bwv[j], c);
        }
    } else {
        int r = bid - 256;               // 0..31
        float4 v  = ((const float4*)(dirs + (size_t)r * DD))[tid];
        float4 g  = ((const float4*)gamma)[tid];
        float4 be = ((const float4*)beta)[tid];
        float s0 = sgnf(v.x), s1 = sgnf(v.y), s2 = sgnf(v.z), s3 = sgnf(v.w);
        ushort4 o;
        o.x = f2bf(s0 * g.x); o.y = f2bf(s1 * g.y);
        o.z = f2bf(s2 * g.z); o.w = f2bf(s3 * g.w);
        ((ushort4*)(WT + (size_t)(HH + r) * DD))[tid] = o;
        float ps = s0 * g.x + s1 * g.y + s2 * g.z + s3 * g.w;
        float pb = s0 * be.x + s1 * be.y + s2 * be.z + s3 * be.w;
#pragma unroll
        for (int off = 32; off; off >>= 1) {
            ps += __shfl_xor(ps, off);
            pb += __shfl_xor(pb, off);
        }
        __shared__ float red[8];
        int wid = tid >> 6, lane = tid & 63;
        if (lane == 0) { red[wid] = ps; red[wid + 4] = pb; }
        __syncthreads();
        if (tid == 0) {
            colsum[HH + r] = red[0] + red[1] + red[2] + red[3];
            bwv[HH + r]    = red[4] + red[5] + red[6] + red[7];
        }
    }
}

// ---------------- K1: fully fused LN-GEMM + epilogue (counted-vmcnt pipeline) ----
// 256 blocks (1/CU), 768 threads (12 waves: 2M x 6N), BM=32, BN=288, BK=64.
// Raw s_barrier with counted vmcnt: x prefetch (2 named reg sets, loop unrolled
// x2) stays in flight ACROSS the barrier (T3/T4); B via global_load_lds
// double-buffered (pre-swizzled source, rule 21). After K-loop: LN-corrected
// 32x288 tile -> LDS, per-row epilogue, out = x + c*dirs[tile].
__global__ __launch_bounds__(768, 3) void k_fused(
    const float* __restrict__ x, const unsigned short* __restrict__ WT,
    const float* __restrict__ colsum, const float* __restrict__ bwv,
    const float* __restrict__ positions, const int* __restrict__ states,
    const float* __restrict__ b1, const float* __restrict__ W2,
    const float* __restrict__ b2, const float* __restrict__ spc,
    const float* __restrict__ sps, const float* __restrict__ dirs,
    const float* __restrict__ ssig, const float* __restrict__ semb,
    const float* __restrict__ smod, const float* __restrict__ oscale,
    float* __restrict__ out) {
    __shared__ short Al[2][BM * BK];        // 2 x 4 KB
    __shared__ short Bl[2][NCOLS * BK];     // 2 x 36 KB
    __shared__ float stats[BM][2];
    float* HPl = (float*)&Bl[0][0];         // 32 x 292 f32 (spills 512B into Bl[1]; both dead)

    int tid  = threadIdx.x;
    int row0 = blockIdx.x * BM;
    int lane = tid & 63;
    int wid  = tid >> 6;                    // 0..11
    int wn = wid % 6, wm = wid / 6;
    int l15 = lane & 15, l4 = lane >> 4;

    // A staging ids (threads 0..255 = waves 0..3): 8 threads/row, 8 floats each
    int rA = tid >> 3;                      // 0..31
    int g8 = tid & 7;
    const float* xrow = x + (size_t)(row0 + rA) * DD + g8 * 8;
    int aoff = (rA * 128 + g8 * 16) ^ ((rA & 7) << 4);

    float s = 0.f, sq = 0.f;
    float4 x0a, x0b, x1a, x1b;              // two named prefetch sets (rule 20)
    f32x4 acc[3];
#pragma unroll
    for (int nf = 0; nf < 3; ++nf) acc[nf] = (f32x4){0.f, 0.f, 0.f, 0.f};

#define STAGE_B(kt, buf)                                                         \
    {                                                                            \
        _Pragma("unroll")                                                        \
        for (int ci = 0; ci < 3; ++ci) {                                         \
            int li = ci * 768 + tid;                                             \
            int r  = li >> 3;                                                    \
            int g  = li & 7;                                                     \
            const unsigned short* src =                                          \
                WT + (size_t)r * DD + (kt) * 64 + ((g * 8) ^ ((r & 7) << 3));    \
            __builtin_amdgcn_global_load_lds(                                    \
                (const __attribute__((address_space(1))) void*)(const void*)src, \
                (__attribute__((address_space(3))) void*)(void*)(Bl[buf] + li * 8), \
                16, 0, 0);                                                       \
        }                                                                        \
    }

#define WRITE_A(XA, XB, buf)                                                    \
    if (wid < 4) {                                                              \
        s  += (XA.x + XA.y + XA.z + XA.w) + (XB.x + XB.y + XB.z + XB.w);        \
        sq += (XA.x*XA.x + XA.y*XA.y + XA.z*XA.z + XA.w*XA.w)                   \
            + (XB.x*XB.x + XB.y*XB.y + XB.z*XB.z + XB.w*XB.w);                  \
        ushort8_t w;                                                            \
        w[0] = f2bf(XA.x); w[1] = f2bf(XA.y); w[2] = f2bf(XA.z); w[3] = f2bf(XA.w); \
        w[4] = f2bf(XB.x); w[5] = f2bf(XB.y); w[6] = f2bf(XB.z); w[7] = f2bf(XB.w); \
        *(ushort8_t*)((char*)Al[buf] + aoff) = w;                               \
    }

#define COMPUTE(CUR)                                                            \
    _Pragma("unroll")                                                           \
    for (int ks = 0; ks < 2; ++ks) {                                            \
        int ra = wm * 16 + l15;                                                 \
        int ca = (ks * 64 + l4 * 16) ^ ((ra & 7) << 4);                         \
        bf16x8 av = *(const bf16x8*)((const char*)Al[CUR] + ra * 128 + ca);     \
        bf16x8 bv[3];                                                           \
        _Pragma("unroll")                                                       \
        for (int nf = 0; nf < 3; ++nf) {                                        \
            int rb = wn * 48 + nf * 16 + l15;                                   \
            int cb = (ks * 64 + l4 * 16) ^ ((rb & 7) << 4);                     \
            bv[nf] = *(const bf16x8*)((const char*)Bl[CUR] + rb * 128 + cb);    \
        }                                                                       \
        _Pragma("unroll")                                                       \
        for (int nf = 0; nf < 3; ++nf)                                          \
            acc[nf] = __builtin_amdgcn_mfma_f32_16x16x32_bf16(av, bv[nf], acc[nf], 0, 0, 0); \
    }

// STEP: iter kt consumes XC (tile kt+1 regs), issues tile kt+2 into XI.
// Issue order pinned: STAGE_B first, then x loads -> at barrier the per-thread
// vmem FIFO (staging waves) = [B(3) older, x(2) newest] -> vmcnt(2) drains B.
#define STEP(kt, XCa, XCb, XIa, XIb, CUR, NXT)                                  \
    {                                                                           \
        if ((kt) <= 14) STAGE_B((kt) + 1, NXT);                                 \
        __builtin_amdgcn_sched_barrier(0);                                      \
        if ((kt) <= 13 && wid < 4) {                                            \
            XIa = ((const float4*)(xrow + ((kt) + 2) * 64))[0];                 \
            XIb = ((const float4*)(xrow + ((kt) + 2) * 64))[1];                 \
        }                                                                       \
        COMPUTE(CUR);                                                           \
        if ((kt) <= 14) WRITE_A(XCa, XCb, NXT);                                 \
        if ((kt) <= 13) {                                                       \
            if (wid < 4) asm volatile("s_waitcnt vmcnt(2) lgkmcnt(0)" ::: "memory"); \
            else         asm volatile("s_waitcnt vmcnt(0)" ::: "memory");       \
        } else if ((kt) == 14) {                                                \
            if (wid < 4) asm volatile("s_waitcnt vmcnt(0) lgkmcnt(0)" ::: "memory"); \
            else         asm volatile("s_waitcnt vmcnt(0)" ::: "memory");       \
        }                                                                       \
        if ((kt) <= 14) {                                                       \
            __builtin_amdgcn_s_barrier();                                       \
            __builtin_amdgcn_sched_barrier(0);                                  \
        }                                                                       \
    }

    // Prologue: tile0 -> Al[0] (x0 set), tile1 -> x1 set (in flight), B0 -> Bl[0]
    if (wid < 4) {
        x0a = ((const float4*)(xrow))[0];
        x0b = ((const float4*)(xrow))[1];
        x1a = ((const float4*)(xrow + 64))[0];
        x1b = ((const float4*)(xrow + 64))[1];
    }
    STAGE_B(0, 0);
    WRITE_A(x0a, x0b, 0);
    __syncthreads();   // full drain (prologue only)

    for (int kt = 0; kt < 16; kt += 2) {
        STEP(kt,     x1a, x1b, x0a, x0b, 0, 1);   // consumes tile kt+1 (set1), issues kt+2 (set0)
        STEP(kt + 1, x0a, x0b, x1a, x1b, 1, 0);   // consumes tile kt+2 (set0), issues kt+3 (set1)
    }
    __syncthreads();   // final drain after kt=15 compute

    // LN stats finalize (8 staging threads per row are adjacent lanes)
    if (wid < 4) {
        s  += __shfl_xor(s, 1);  s  += __shfl_xor(s, 2);  s  += __shfl_xor(s, 4);
        sq += __shfl_xor(sq, 1); sq += __shfl_xor(sq, 2); sq += __shfl_xor(sq, 4);
        if (g8 == 0) {
            float mu  = s * (1.0f / DD);
            float var = sq * (1.0f / DD) - mu * mu;
            stats[rA][0] = mu;
            stats[rA][1] = rsqrtf(var + 1e-5f);
        }
    }
    __syncthreads();

    // LN-corrected tile -> HPl (D frag: col=lane&15, row=(lane>>4)*4+i)
#pragma unroll
    for (int nf = 0; nf < 3; ++nf) {
        int colg = wn * 48 + nf * 16 + l15;
        float cs = colsum[colg];
        float bw = bwv[colg];
        int r0 = wm * 16 + l4 * 4;
#pragma unroll
        for (int i = 0; i < 4; ++i) {
            float mu = stats[r0 + i][0], rs = stats[r0 + i][1];
            HPl[(r0 + i) * HPS + colg] = rs * acc[nf][i] - mu * rs * cs + bw;
        }
    }
    __syncthreads();

    // ---- per-row epilogue; wave w handles rows w, w+12, w+24 ----
    float4 b1v = ((const float4*)b1)[lane];
    float w2a[4], w2b[4];
#pragma unroll
    for (int i = 0; i < 4; ++i) {
        int j = lane * 4 + i;
        w2a[i] = W2[2 * j];
        w2b[i] = W2[2 * j + 1];
    }
    float tvs[2] = {0.f, 0.f};
    if (lane < NTT) {
#pragma unroll
        for (int s2 = 0; s2 < 2; ++s2) {
            float d0 = 0.f;
#pragma unroll
            for (int k = 0; k < 8; ++k) d0 += semb[s2 * 8 + k] * ssig[lane * 8 + k];
            tvs[s2] = 1.0f / (1.0f + expf(-d0));
        }
    }
    float osc = oscale[0];
    float bb0 = b2[0], bb1 = b2[1];

    for (int r = wid; r < BM; r += NW) {
        int row = row0 + r;
        float4 hv = *(const float4*)&HPl[r * HPS + lane * 4];
        float hs[4] = {hv.x, hv.y, hv.z, hv.w};
        float bs[4] = {b1v.x, b1v.y, b1v.z, b1v.w};
        float sa = 0.f, sb2 = 0.f;
#pragma unroll
        for (int i = 0; i < 4; ++i) {
            float h = hs[i] + bs[i];
            float g = 0.5f * h * (1.0f + erff(h * 0.70710678118654752f));
            sa  += g * w2a[i];
            sb2 += g * w2b[i];
        }
#pragma unroll
        for (int off = 32; off; off >>= 1) {
            sa  += __shfl_xor(sa, off);
            sb2 += __shfl_xor(sb2, off);
        }
        float av2 = tanhf(sa + bb0);
        float bv2 = tanhf(sb2 + bb1);

        int st = states[row];
        float comb;
        if (lane < NTT) {
            float content = HPl[r * HPS + HH + lane];
            float pn = positions[row] * ((float)NTT / 2048.0f);
            float spv = bspline((pn - (float)lane) * 0.5f);
            comb = content * spv * tvs[st];
        } else {
            comb = -__builtin_inff();
        }
        int bi = lane;
#pragma unroll
        for (int off = 32; off; off >>= 1) {
            float ov = __shfl_xor(comb, off);
            int   oi = __shfl_xor(bi, off);
            if (ov > comb || (ov == comb && oi < bi)) { comb = ov; bi = oi; }
        }
        int ia = (int)((av2 + 1.0f) * 8.0f); ia = ia < 0 ? 0 : (ia > 15 ? 15 : ia);
        int ib = (int)((bv2 + 1.0f) * 8.0f); ib = ib < 0 ? 0 : (ib > 15 ? 15 : ib);
        const float* cc = spc + (((size_t)bi * 16 + ia) * 16 + ib) * 3;
        float c0 = ternf(cc[0]), c1 = ternf(cc[1]), c2 = ternf(cc[2]);
        float la = (av2 + 1.0f - (float)ia * 0.125f) * 8.0f;
        float lb = (bv2 + 1.0f - (float)ib * 0.125f) * 8.0f;
        float scale = (c0 + c1 * la + c2 * lb) * sps[bi];
        float cr = scale * smod[st * NTT + bi] * osc;

        const float4* xr = (const float4*)(x + (size_t)row * DD);
        const float4* dr = (const float4*)(dirs + (size_t)bi * DD);
        float4* orow = (float4*)(out + (size_t)row * DD);
#pragma unroll
        for (int i = 0; i < 4; ++i) {
            int idx = i * 64 + lane;
            float4 xv = xr[idx];
            float4 dv = dr[idx];
            float4 o;
            o.x = fmaf(cr, dv.x, xv.x);
            o.y = fmaf(cr, dv.y, xv.y);
            o.z = fmaf(cr, dv.z, xv.z);
            o.w = fmaf(cr, dv.w, xv.w);
            orow[idx] = o;
        }
    }
#undef STAGE_B
#undef WRITE_A
#undef COMPUTE
#undef STEP
}

extern "C" void kernel_launch(void* const* d_in, const int* in_sizes, int n_in,
                              void* d_out, int out_size, void* d_ws, size_t ws_size,
                              hipStream_t stream) {
    const float* x     = (const float*)d_in[0];
    const float* pos   = (const float*)d_in[1];
    const int*   st    = (const int*)d_in[2];
    const float* gam   = (const float*)d_in[3];
    const float* bet   = (const float*)d_in[4];
    const float* W1    = (const float*)d_in[5];
    const float* b1    = (const float*)d_in[6];
    const float* W2    = (const float*)d_in[7];
    const float* b2    = (const float*)d_in[8];
    const float* spc   = (const float*)d_in[9];
    const float* sps   = (const float*)d_in[10];
    const float* dirs  = (const float*)d_in[11];
    const float* ssig  = (const float*)d_in[12];
    const float* semb  = (const float*)d_in[13];
    const float* smod  = (const float*)d_in[14];
    const float* oscal = (const float*)d_in[15];
    float* out = (float*)d_out;

    char* ws = (char*)d_ws;
    unsigned short* WT = (unsigned short*)ws;                  // 288*1024 bf16 = 576 KiB
    float* colsum = (float*)(ws + 589824);                     // 288 f32
    float* bwv    = (float*)(ws + 589824 + 288 * 4);           // 288 f32 (contiguous)

    hipMemsetAsync(colsum, 0, 2 * 288 * sizeof(float), stream);
    k_prep<<<288, 256, 0, stream>>>(W1, dirs, gam, bet, WT, colsum, bwv);
    k_fused<<<NROWS / BM, 768, 0, stream>>>(x, WT, colsum, bwv, pos, st, b1, W2, b2,
                                            spc, sps, dirs, ssig, semb, smod, oscal, out);
}

// Round 5
// 41.325 us; speedup vs baseline: 2.0602x; 1.0117x over previous
//
#include <hip/hip_runtime.h>
#include <math.h>

// Problem dims (fixed by setup_inputs)
#define NROWS 8192   // B*T = 4*2048
#define DD    1024
#define HH    256
#define NTT   32
#define NCOLS 288    // HH + NTT
#define BM    32
#define BK    64
#define NW    12     // waves in fused kernel (768 threads)
#define HPS   292    // HP LDS row stride (floats), padded to spread banks

typedef __attribute__((ext_vector_type(8))) __bf16 bf16x8;
typedef __attribute__((ext_vector_type(4))) float f32x4;
typedef __attribute__((ext_vector_type(8))) unsigned short ushort8_t;

static __device__ __forceinline__ unsigned short f2bf(float f) {
    unsigned int u = __float_as_uint(f);
    unsigned int r = (u + 0x7fffu + ((u >> 16) & 1u)) >> 16;
    return (unsigned short)r;
}

static __device__ __forceinline__ float bf2f(unsigned short u) {
    return __uint_as_float(((unsigned int)u) << 16);
}

static __device__ __forceinline__ float sgnf(float x) {
    return x > 0.0f ? 1.0f : (x < 0.0f ? -1.0f : 0.0f);
}

static __device__ __forceinline__ float ternf(float x) {
    return x > 0.3f ? 1.0f : (x < -0.3f ? -1.0f : 0.0f);
}

static __device__ __forceinline__ float bspline(float u) {
    float t = fabsf(u);
    if (t < 1.0f) return 0.66666666666666663f - t * t + 0.5f * t * t * t;
    if (t < 2.0f) { float w = 2.0f - t; return 0.16666666666666666f * w * w * w; }
    return 0.0f;
}

// ---------------- K0: merged prep (grid 288) ----------------
__global__ __launch_bounds__(256) void k_prep(const float* __restrict__ W1,
                                              const float* __restrict__ dirs,
                                              const float* __restrict__ gamma,
                                              const float* __restrict__ beta,
                                              unsigned short* __restrict__ WT,
                                              float* __restrict__ colsum,
                                              float* __restrict__ bwv) {
    int bid = blockIdx.x;
    int tid = threadIdx.x;
    if (bid < 256) {
        __shared__ float tile[32][33];
        __shared__ float redg[8][32];
        __shared__ float redb[8][32];
        int ktile = bid & 31;            // d tiles of 32
        int ntile = bid >> 5;            // j tiles of 32
        int tx = tid & 31;
        int ty = tid >> 5;               // 0..7
        float sg = 0.f, sb = 0.f;
#pragma unroll
        for (int i = 0; i < 4; ++i) {
            int k = ktile * 32 + ty + i * 8;
            int n = ntile * 32 + tx;
            float w = W1[(size_t)k * HH + n];        // coalesced over n
            float gk = gamma[k];
            tile[ty + i * 8][tx] = w * gk;
            sg += w * gk;
            sb += w * beta[k];
        }
        redg[ty][tx] = sg;
        redb[ty][tx] = sb;
        __syncthreads();
#pragma unroll
        for (int i = 0; i < 4; ++i) {
            int n = ntile * 32 + ty + i * 8;
            int k = ktile * 32 + tx;
            WT[(size_t)n * DD + k] = f2bf(tile[tx][ty + i * 8]);  // coalesced over k
        }
        if (ty == 0) {
            float a = 0.f, c = 0.f;
#pragma unroll
            for (int k = 0; k < 8; ++k) { a += redg[k][tx]; c += redb[k][tx]; }
            int j = ntile * 32 + tx;
            atomicAdd(&colsum[j], a);
            atomicAdd(&bwv[j], c);
        }
    } else {
        int r = bid - 256;               // 0..31
        float4 v  = ((const float4*)(dirs + (size_t)r * DD))[tid];
        float4 g  = ((const float4*)gamma)[tid];
        float4 be = ((const float4*)beta)[tid];
        float s0 = sgnf(v.x), s1 = sgnf(v.y), s2 = sgnf(v.z), s3 = sgnf(v.w);
        ushort4 o;
        o.x = f2bf(s0 * g.x); o.y = f2bf(s1 * g.y);
        o.z = f2bf(s2 * g.z); o.w = f2bf(s3 * g.w);
        ((ushort4*)(WT + (size_t)(HH + r) * DD))[tid] = o;
        float ps = s0 * g.x + s1 * g.y + s2 * g.z + s3 * g.w;
        float pb = s0 * be.x + s1 * be.y + s2 * be.z + s3 * be.w;
#pragma unroll
        for (int off = 32; off; off >>= 1) {
            ps += __shfl_xor(ps, off);
            pb += __shfl_xor(pb, off);
        }
        __shared__ float red[8];
        int wid = tid >> 6, lane = tid & 63;
        if (lane == 0) { red[wid] = ps; red[wid + 4] = pb; }
        __syncthreads();
        if (tid == 0) {
            colsum[HH + r] = red[0] + red[1] + red[2] + red[3];
            bwv[HH + r]    = red[4] + red[5] + red[6] + red[7];
        }
    }
}

// ---------------- K1: fused LN-GEMM + epilogue, persistent bf16 X in LDS ----
// 256 blocks (1/CU), 768 threads (12 waves: 2M x 6N), BM=32, BN=288, BK=64.
// Xl[32][1024] bf16 (64KB, XOR-swizzled, stride 2048B) holds the whole x tile:
// written once per K-step column, read as MFMA A-frags AND re-read by the
// epilogue (no HBM x re-read). B double-buffered via global_load_lds.
// Counted-vmcnt schedule (T3/T4) from R4, unchanged.
__global__ __launch_bounds__(768, 3) void k_fused(
    const float* __restrict__ x, const unsigned short* __restrict__ WT,
    const float* __restrict__ colsum, const float* __restrict__ bwv,
    const float* __restrict__ positions, const int* __restrict__ states,
    const float* __restrict__ b1, const float* __restrict__ W2,
    const float* __restrict__ b2, const float* __restrict__ spc,
    const float* __restrict__ sps, const float* __restrict__ dirs,
    const float* __restrict__ ssig, const float* __restrict__ semb,
    const float* __restrict__ smod, const float* __restrict__ oscale,
    float* __restrict__ out) {
    __shared__ short Xl[BM * DD];           // 64 KB persistent bf16 x tile
    __shared__ short Bl[2][NCOLS * BK];     // 2 x 36 KB
    __shared__ float stats[BM][2];
    float* HPl = (float*)&Bl[0][0];         // 32 x 292 f32 (spills 512B into Bl[1]; both dead)

    int tid  = threadIdx.x;
    int row0 = blockIdx.x * BM;
    int lane = tid & 63;
    int wid  = tid >> 6;                    // 0..11
    int wn = wid % 6, wm = wid / 6;
    int l15 = lane & 15, l4 = lane >> 4;

    // A staging ids (threads 0..255 = waves 0..3): 8 threads/row, 8 floats each
    int rA = tid >> 3;                      // 0..31
    int g8 = tid & 7;
    const float* xrow = x + (size_t)(row0 + rA) * DD + g8 * 8;
    int xbase = rA * 2048 + ((g8 * 16) ^ ((rA & 7) << 4));   // byte base in Xl

    float s = 0.f, sq = 0.f;
    float4 x0a, x0b, x1a, x1b;              // two named prefetch sets (rule 20)
    f32x4 acc[3];
#pragma unroll
    for (int nf = 0; nf < 3; ++nf) acc[nf] = (f32x4){0.f, 0.f, 0.f, 0.f};

#define STAGE_B(kt, buf)                                                         \
    {                                                                            \
        _Pragma("unroll")                                                        \
        for (int ci = 0; ci < 3; ++ci) {                                         \
            int li = ci * 768 + tid;                                             \
            int r  = li >> 3;                                                    \
            int g  = li & 7;                                                     \
            const unsigned short* src =                                          \
                WT + (size_t)r * DD + (kt) * 64 + ((g * 8) ^ ((r & 7) << 3));    \
            __builtin_amdgcn_global_load_lds(                                    \
                (const __attribute__((address_space(1))) void*)(const void*)src, \
                (__attribute__((address_space(3))) void*)(void*)(Bl[buf] + li * 8), \
                16, 0, 0);                                                       \
        }                                                                        \
    }

// write tile (KT)'s 64 k-columns into Xl at column block KT
#define WRITE_A(XA, XB, KT)                                                     \
    if (wid < 4) {                                                              \
        s  += (XA.x + XA.y + XA.z + XA.w) + (XB.x + XB.y + XB.z + XB.w);        \
        sq += (XA.x*XA.x + XA.y*XA.y + XA.z*XA.z + XA.w*XA.w)                   \
            + (XB.x*XB.x + XB.y*XB.y + XB.z*XB.z + XB.w*XB.w);                  \
        ushort8_t w;                                                            \
        w[0] = f2bf(XA.x); w[1] = f2bf(XA.y); w[2] = f2bf(XA.z); w[3] = f2bf(XA.w); \
        w[4] = f2bf(XB.x); w[5] = f2bf(XB.y); w[6] = f2bf(XB.z); w[7] = f2bf(XB.w); \
        *(ushort8_t*)((char*)Xl + xbase + (KT) * 128) = w;                      \
    }

#define COMPUTE(KT, CUR)                                                        \
    _Pragma("unroll")                                                           \
    for (int ks = 0; ks < 2; ++ks) {                                            \
        int ra = wm * 16 + l15;                                                 \
        int ca = (KT) * 128 + ((ks * 64 + l4 * 16) ^ ((ra & 7) << 4));          \
        bf16x8 av = *(const bf16x8*)((const char*)Xl + ra * 2048 + ca);         \
        bf16x8 bv[3];                                                           \
        _Pragma("unroll")                                                       \
        for (int nf = 0; nf < 3; ++nf) {                                        \
            int rb = wn * 48 + nf * 16 + l15;                                   \
            int cb = (ks * 64 + l4 * 16) ^ ((rb & 7) << 4);                     \
            bv[nf] = *(const bf16x8*)((const char*)Bl[CUR] + rb * 128 + cb);    \
        }                                                                       \
        _Pragma("unroll")                                                       \
        for (int nf = 0; nf < 3; ++nf)                                          \
            acc[nf] = __builtin_amdgcn_mfma_f32_16x16x32_bf16(av, bv[nf], acc[nf], 0, 0, 0); \
    }

// STEP kt: stage B(kt+1), issue x tile kt+2, compute kt, write x tile kt+1.
// Staging-wave FIFO at barrier = [B(3) older, x(2) newest] -> vmcnt(2).
#define STEP(kt, XCa, XCb, XIa, XIb, CUR, NXT)                                  \
    {                                                                           \
        if ((kt) <= 14) STAGE_B((kt) + 1, NXT);                                 \
        __builtin_amdgcn_sched_barrier(0);                                      \
        if ((kt) <= 13 && wid < 4) {                                            \
            XIa = ((const float4*)(xrow + ((kt) + 2) * 64))[0];                 \
            XIb = ((const float4*)(xrow + ((kt) + 2) * 64))[1];                 \
        }                                                                       \
        COMPUTE(kt, CUR);                                                       \
        if ((kt) <= 14) WRITE_A(XCa, XCb, (kt) + 1);                            \
        if ((kt) <= 13) {                                                       \
            if (wid < 4) asm volatile("s_waitcnt vmcnt(2) lgkmcnt(0)" ::: "memory"); \
            else         asm volatile("s_waitcnt vmcnt(0)" ::: "memory");       \
        } else if ((kt) == 14) {                                                \
            if (wid < 4) asm volatile("s_waitcnt vmcnt(0) lgkmcnt(0)" ::: "memory"); \
            else         asm volatile("s_waitcnt vmcnt(0)" ::: "memory");       \
        }                                                                       \
        if ((kt) <= 14) {                                                       \
            __builtin_amdgcn_s_barrier();                                       \
            __builtin_amdgcn_sched_barrier(0);                                  \
        }                                                                       \
    }

    // Prologue: B0 first, then x0 (tile0), x1 (tile1) -> FIFO [B0(3), x0(2), x1(2)]
    STAGE_B(0, 0);
    __builtin_amdgcn_sched_barrier(0);
    if (wid < 4) {
        x0a = ((const float4*)(xrow))[0];
        x0b = ((const float4*)(xrow))[1];
        x1a = ((const float4*)(xrow + 64))[0];
        x1b = ((const float4*)(xrow + 64))[1];
    }
    WRITE_A(x0a, x0b, 0);   // compiler waits through x0; B0+x1 may remain
    if (wid < 4) asm volatile("s_waitcnt vmcnt(2) lgkmcnt(0)" ::: "memory");
    else         asm volatile("s_waitcnt vmcnt(0)" ::: "memory");
    __builtin_amdgcn_s_barrier();
    __builtin_amdgcn_sched_barrier(0);

    for (int kt = 0; kt < 16; kt += 2) {
        STEP(kt,     x1a, x1b, x0a, x0b, 0, 1);   // consumes tile kt+1 (set1), issues kt+2 (set0)
        STEP(kt + 1, x0a, x0b, x1a, x1b, 1, 0);   // consumes tile kt+2 (set0), issues kt+3 (set1)
    }
    __syncthreads();   // final drain after kt=15 compute

    // LN stats finalize (8 staging threads per row are adjacent lanes)
    if (wid < 4) {
        s  += __shfl_xor(s, 1);  s  += __shfl_xor(s, 2);  s  += __shfl_xor(s, 4);
        sq += __shfl_xor(sq, 1); sq += __shfl_xor(sq, 2); sq += __shfl_xor(sq, 4);
        if (g8 == 0) {
            float mu  = s * (1.0f / DD);
            float var = sq * (1.0f / DD) - mu * mu;
            stats[rA][0] = mu;
            stats[rA][1] = rsqrtf(var + 1e-5f);
        }
    }
    __syncthreads();

    // LN-corrected tile -> HPl (D frag: col=lane&15, row=(lane>>4)*4+i)
#pragma unroll
    for (int nf = 0; nf < 3; ++nf) {
        int colg = wn * 48 + nf * 16 + l15;
        float cs = colsum[colg];
        float bw = bwv[colg];
        int r0 = wm * 16 + l4 * 4;
#pragma unroll
        for (int i = 0; i < 4; ++i) {
            float mu = stats[r0 + i][0], rs = stats[r0 + i][1];
            HPl[(r0 + i) * HPS + colg] = rs * acc[nf][i] - mu * rs * cs + bw;
        }
    }
    __syncthreads();

    // ---- per-row epilogue; wave w handles rows w, w+12, w+24 ----
    float4 b1v = ((const float4*)b1)[lane];
    float w2a[4], w2b[4];
#pragma unroll
    for (int i = 0; i < 4; ++i) {
        int j = lane * 4 + i;
        w2a[i] = W2[2 * j];
        w2b[i] = W2[2 * j + 1];
    }
    float tvs[2] = {0.f, 0.f};
    if (lane < NTT) {
#pragma unroll
        for (int s2 = 0; s2 < 2; ++s2) {
            float d0 = 0.f;
#pragma unroll
            for (int k = 0; k < 8; ++k) d0 += semb[s2 * 8 + k] * ssig[lane * 8 + k];
            tvs[s2] = 1.0f / (1.0f + expf(-d0));
        }
    }
    float osc = oscale[0];
    float bb0 = b2[0], bb1 = b2[1];

    for (int r = wid; r < BM; r += NW) {
        int row = row0 + r;
        float4 hv = *(const float4*)&HPl[r * HPS + lane * 4];
        float hs[4] = {hv.x, hv.y, hv.z, hv.w};
        float bs[4] = {b1v.x, b1v.y, b1v.z, b1v.w};
        float sa = 0.f, sb2 = 0.f;
#pragma unroll
        for (int i = 0; i < 4; ++i) {
            float h = hs[i] + bs[i];
            float g = 0.5f * h * (1.0f + erff(h * 0.70710678118654752f));
            sa  += g * w2a[i];
            sb2 += g * w2b[i];
        }
#pragma unroll
        for (int off = 32; off; off >>= 1) {
            sa  += __shfl_xor(sa, off);
            sb2 += __shfl_xor(sb2, off);
        }
        float av2 = tanhf(sa + bb0);
        float bv2 = tanhf(sb2 + bb1);

        int st = states[row];
        float comb;
        if (lane < NTT) {
            float content = HPl[r * HPS + HH + lane];
            float pn = positions[row] * ((float)NTT / 2048.0f);
            float spv = bspline((pn - (float)lane) * 0.5f);
            comb = content * spv * tvs[st];
        } else {
            comb = -__builtin_inff();
        }
        int bi = lane;
#pragma unroll
        for (int off = 32; off; off >>= 1) {
            float ov = __shfl_xor(comb, off);
            int   oi = __shfl_xor(bi, off);
            if (ov > comb || (ov == comb && oi < bi)) { comb = ov; bi = oi; }
        }
        int ia = (int)((av2 + 1.0f) * 8.0f); ia = ia < 0 ? 0 : (ia > 15 ? 15 : ia);
        int ib = (int)((bv2 + 1.0f) * 8.0f); ib = ib < 0 ? 0 : (ib > 15 ? 15 : ib);
        const float* cc = spc + (((size_t)bi * 16 + ia) * 16 + ib) * 3;
        float c0 = ternf(cc[0]), c1 = ternf(cc[1]), c2 = ternf(cc[2]);
        float la = (av2 + 1.0f - (float)ia * 0.125f) * 8.0f;
        float lb = (bv2 + 1.0f - (float)ib * 0.125f) * 8.0f;
        float scale = (c0 + c1 * la + c2 * lb) * sps[bi];
        float cr = scale * smod[st * NTT + bi] * osc;

        // x from LDS (bf16), dir from global; out = x + cr*dir
        int swzr = (r & 7) << 4;
        const float4* dr = (const float4*)(dirs + (size_t)bi * DD);
        float4* orow = (float4*)(out + (size_t)row * DD);
#pragma unroll
        for (int i = 0; i < 4; ++i) {
            int idx = i * 64 + lane;                  // float4 index in row
            int byteoff = r * 2048 + ((idx * 8) ^ swzr);
            ushort4 xv = *(const ushort4*)((const char*)Xl + byteoff);
            float4 dv = dr[idx];
            float4 o;
            o.x = fmaf(cr, dv.x, bf2f(xv.x));
            o.y = fmaf(cr, dv.y, bf2f(xv.y));
            o.z = fmaf(cr, dv.z, bf2f(xv.z));
            o.w = fmaf(cr, dv.w, bf2f(xv.w));
            orow[idx] = o;
        }
    }
#undef STAGE_B
#undef WRITE_A
#undef COMPUTE
#undef STEP
}

extern "C" void kernel_launch(void* const* d_in, const int* in_sizes, int n_in,
                              void* d_out, int out_size, void* d_ws, size_t ws_size,
                              hipStream_t stream) {
    const float* x     = (const float*)d_in[0];
    const float* pos   = (const float*)d_in[1];
    const int*   st    = (const int*)d_in[2];
    const float* gam   = (const float*)d_in[3];
    const float* bet   = (const float*)d_in[4];
    const float* W1    = (const float*)d_in[5];
    const float* b1    = (const float*)d_in[6];
    const float* W2    = (const float*)d_in[7];
    const float* b2    = (const float*)d_in[8];
    const float* spc   = (const float*)d_in[9];
    const float* sps   = (const float*)d_in[10];
    const float* dirs  = (const float*)d_in[11];
    const float* ssig  = (const float*)d_in[12];
    const float* semb  = (const float*)d_in[13];
    const float* smod  = (const float*)d_in[14];
    const float* oscal = (const float*)d_in[15];
    float* out = (float*)d_out;

    char* ws = (char*)d_ws;
    unsigned short* WT = (unsigned short*)ws;                  // 288*1024 bf16 = 576 KiB
    float* colsum = (float*)(ws + 589824);                     // 288 f32
    float* bwv    = (float*)(ws + 589824 + 288 * 4);           // 288 f32 (contiguous)

    hipMemsetAsync(colsum, 0, 2 * 288 * sizeof(float), stream);
    k_prep<<<288, 256, 0, stream>>>(W1, dirs, gam, bet, WT, colsum, bwv);
    k_fused<<<NROWS / BM, 768, 0, stream>>>(x, WT, colsum, bwv, pos, st, b1, W2, b2,
                                            spc, sps, dirs, ssig, semb, smod, oscal, out);
}

// Round 6
// 41.312 us; speedup vs baseline: 2.0608x; 1.0003x over previous
//
#include <hip/hip_runtime.h>
#include <math.h>

// Problem dims (fixed by setup_inputs)
#define NROWS 8192   // B*T = 4*2048
#define DD    1024
#define HH    256
#define NTT   32
#define NCOLS 288    // HH + NTT
#define BM    32
#define BK    64
#define NTHR  576    // 9 waves
#define NW    9
#define HPS   292    // HP LDS row stride (floats), padded to spread banks

typedef __attribute__((ext_vector_type(8))) __bf16 bf16x8;
typedef __attribute__((ext_vector_type(4))) float f32x4;
typedef __attribute__((ext_vector_type(8))) unsigned short ushort8_t;

static __device__ __forceinline__ unsigned short f2bf(float f) {
    unsigned int u = __float_as_uint(f);
    unsigned int r = (u + 0x7fffu + ((u >> 16) & 1u)) >> 16;
    return (unsigned short)r;
}

static __device__ __forceinline__ float bf2f(unsigned short u) {
    return __uint_as_float(((unsigned int)u) << 16);
}

static __device__ __forceinline__ float sgnf(float x) {
    return x > 0.0f ? 1.0f : (x < 0.0f ? -1.0f : 0.0f);
}

static __device__ __forceinline__ float ternf(float x) {
    return x > 0.3f ? 1.0f : (x < -0.3f ? -1.0f : 0.0f);
}

static __device__ __forceinline__ float bspline(float u) {
    float t = fabsf(u);
    if (t < 1.0f) return 0.66666666666666663f - t * t + 0.5f * t * t * t;
    if (t < 2.0f) { float w = 2.0f - t; return 0.16666666666666666f * w * w * w; }
    return 0.0f;
}

// ---------------- K0: merged prep (grid 288), NO atomics ----------------
// blocks 0..255 (ktile=bid&31, ntile=bid>>5): WT[j][d]=gamma[d]*W1[d][j] (bf16
// transpose) + partial colsumP[ktile][j], bwP[ktile][j] (conflict-free).
// blocks 256..287: WT rows 256..287 = gamma*sign(dirs); full sums at partial
// slot k=0, zeros at k=1..31.
__global__ __launch_bounds__(256) void k_prep(const float* __restrict__ W1,
                                              const float* __restrict__ dirs,
                                              const float* __restrict__ gamma,
                                              const float* __restrict__ beta,
                                              unsigned short* __restrict__ WT,
                                              float* __restrict__ colsumP,
                                              float* __restrict__ bwP) {
    int bid = blockIdx.x;
    int tid = threadIdx.x;
    if (bid < 256) {
        __shared__ float tile[32][33];
        __shared__ float redg[8][32];
        __shared__ float redb[8][32];
        int ktile = bid & 31;            // d tiles of 32
        int ntile = bid >> 5;            // j tiles of 32
        int tx = tid & 31;
        int ty = tid >> 5;               // 0..7
        float sg = 0.f, sb = 0.f;
#pragma unroll
        for (int i = 0; i < 4; ++i) {
            int k = ktile * 32 + ty + i * 8;
            int n = ntile * 32 + tx;
            float w = W1[(size_t)k * HH + n];        // coalesced over n
            float gk = gamma[k];
            tile[ty + i * 8][tx] = w * gk;
            sg += w * gk;
            sb += w * beta[k];
        }
        redg[ty][tx] = sg;
        redb[ty][tx] = sb;
        __syncthreads();
#pragma unroll
        for (int i = 0; i < 4; ++i) {
            int n = ntile * 32 + ty + i * 8;
            int k = ktile * 32 + tx;
            WT[(size_t)n * DD + k] = f2bf(tile[tx][ty + i * 8]);  // coalesced over k
        }
        if (ty == 0) {
            float a = 0.f, c = 0.f;
#pragma unroll
            for (int k = 0; k < 8; ++k) { a += redg[k][tx]; c += redb[k][tx]; }
            int j = ntile * 32 + tx;
            colsumP[ktile * NCOLS + j] = a;
            bwP[ktile * NCOLS + j]     = c;
        }
    } else {
        int r = bid - 256;               // 0..31
        float4 v  = ((const float4*)(dirs + (size_t)r * DD))[tid];
        float4 g  = ((const float4*)gamma)[tid];
        float4 be = ((const float4*)beta)[tid];
        float s0 = sgnf(v.x), s1 = sgnf(v.y), s2 = sgnf(v.z), s3 = sgnf(v.w);
        ushort4 o;
        o.x = f2bf(s0 * g.x); o.y = f2bf(s1 * g.y);
        o.z = f2bf(s2 * g.z); o.w = f2bf(s3 * g.w);
        ((ushort4*)(WT + (size_t)(HH + r) * DD))[tid] = o;
        float ps = s0 * g.x + s1 * g.y + s2 * g.z + s3 * g.w;
        float pb = s0 * be.x + s1 * be.y + s2 * be.z + s3 * be.w;
#pragma unroll
        for (int off = 32; off; off >>= 1) {
            ps += __shfl_xor(ps, off);
            pb += __shfl_xor(pb, off);
        }
        __shared__ float red[8];
        int wid = tid >> 6, lane = tid & 63;
        if (lane == 0) { red[wid] = ps; red[wid + 4] = pb; }
        if (tid < 31) {                  // zero partial slots k=1..31
            colsumP[(tid + 1) * NCOLS + HH + r] = 0.f;
            bwP[(tid + 1) * NCOLS + HH + r]     = 0.f;
        }
        __syncthreads();
        if (tid == 0) {
            colsumP[HH + r] = red[0] + red[1] + red[2] + red[3];
            bwP[HH + r]     = red[4] + red[5] + red[6] + red[7];
        }
    }
}

// ---------------- K1: fused LN-GEMM + epilogue ----------------
// 256 blocks (1/CU), 576 threads (9 waves, wave-tile 32x32), BM=32, BN=288,
// BK=64. Persistent bf16 Xl[32][1024] (64KB); B double-buffered via
// global_load_lds (pre-swizzled src). Counted-vmcnt schedule (T3/T4).
// Prologue reduces colsumP/bwP partials into LDS (no atomics, no memset).
__global__ __launch_bounds__(NTHR, 1) void k_fused(
    const float* __restrict__ x, const unsigned short* __restrict__ WT,
    const float* __restrict__ colsumP, const float* __restrict__ bwP,
    const float* __restrict__ positions, const int* __restrict__ states,
    const float* __restrict__ b1, const float* __restrict__ W2,
    const float* __restrict__ b2, const float* __restrict__ spc,
    const float* __restrict__ sps, const float* __restrict__ dirs,
    const float* __restrict__ ssig, const float* __restrict__ semb,
    const float* __restrict__ smod, const float* __restrict__ oscale,
    float* __restrict__ out) {
    __shared__ short Xl[BM * DD];           // 64 KB persistent bf16 x tile
    __shared__ short Bl[2][NCOLS * BK];     // 2 x 36 KB
    __shared__ float stats[BM][2];
    __shared__ float Csum_l[NCOLS];
    __shared__ float Bw_l[NCOLS];
    float* HPl = (float*)&Bl[0][0];         // 32 x 292 f32 (aliases Bl; dead then)

    int tid  = threadIdx.x;
    int row0 = blockIdx.x * BM;
    int lane = tid & 63;
    int wid  = tid >> 6;                    // 0..8
    int wn = wid;                           // wave-tile col group (32 cols)
    int l15 = lane & 15, l4 = lane >> 4;

    // ---- prologue reduction: colsum/bw partials -> LDS ----
    if (tid < NCOLS) {
        float a = 0.f;
#pragma unroll 8
        for (int k = 0; k < 32; ++k) a += colsumP[k * NCOLS + tid];
        Csum_l[tid] = a;
    } else if (tid < 2 * NCOLS) {
        int j = tid - NCOLS;
        float c = 0.f;
#pragma unroll 8
        for (int k = 0; k < 32; ++k) c += bwP[k * NCOLS + j];
        Bw_l[j] = c;
    }
    __builtin_amdgcn_sched_barrier(0);      // reduction loads fully drained here

    // A staging ids (threads 0..255 = waves 0..3): 8 threads/row, 8 floats each
    int rA = tid >> 3;                      // 0..31 (only wid<4 uses)
    int g8 = tid & 7;
    const float* xrow = x + (size_t)(row0 + (rA & 31)) * DD + g8 * 8;
    int xbase = (rA & 31) * 2048 + ((g8 * 16) ^ ((rA & 7) << 4));   // byte base in Xl

    float s = 0.f, sq = 0.f;
    float4 x0a, x0b, x1a, x1b;              // two named prefetch sets (rule 20)
    f32x4 acc[2][2];
#pragma unroll
    for (int i = 0; i < 2; ++i)
#pragma unroll
        for (int j = 0; j < 2; ++j) acc[i][j] = (f32x4){0.f, 0.f, 0.f, 0.f};

#define STAGE_B(kt, buf)                                                         \
    {                                                                            \
        _Pragma("unroll")                                                        \
        for (int ci = 0; ci < 4; ++ci) {                                         \
            int li = ci * NTHR + tid;                                            \
            int r  = li >> 3;                                                    \
            int g  = li & 7;                                                     \
            const unsigned short* src =                                          \
                WT + (size_t)r * DD + (kt) * 64 + ((g * 8) ^ ((r & 7) << 3));    \
            __builtin_amdgcn_global_load_lds(                                    \
                (const __attribute__((address_space(1))) void*)(const void*)src, \
                (__attribute__((address_space(3))) void*)(void*)(Bl[buf] + li * 8), \
                16, 0, 0);                                                       \
        }                                                                        \
    }

// write tile (KT)'s 64 k-columns into Xl at column block KT
#define WRITE_A(XA, XB, KT)                                                     \
    if (wid < 4) {                                                              \
        s  += (XA.x + XA.y + XA.z + XA.w) + (XB.x + XB.y + XB.z + XB.w);        \
        sq += (XA.x*XA.x + XA.y*XA.y + XA.z*XA.z + XA.w*XA.w)                   \
            + (XB.x*XB.x + XB.y*XB.y + XB.z*XB.z + XB.w*XB.w);                  \
        ushort8_t w;                                                            \
        w[0] = f2bf(XA.x); w[1] = f2bf(XA.y); w[2] = f2bf(XA.z); w[3] = f2bf(XA.w); \
        w[4] = f2bf(XB.x); w[5] = f2bf(XB.y); w[6] = f2bf(XB.z); w[7] = f2bf(XB.w); \
        *(ushort8_t*)((char*)Xl + xbase + (KT) * 128) = w;                      \
    }

#define COMPUTE(KT, CUR)                                                        \
    _Pragma("unroll")                                                           \
    for (int ks = 0; ks < 2; ++ks) {                                            \
        bf16x8 av[2], bv[2];                                                    \
        _Pragma("unroll")                                                       \
        for (int mf = 0; mf < 2; ++mf) {                                        \
            int ra = mf * 16 + l15;                                             \
            int ca = (KT) * 128 + ((ks * 64 + l4 * 16) ^ ((ra & 7) << 4));      \
            av[mf] = *(const bf16x8*)((const char*)Xl + ra * 2048 + ca);        \
        }                                                                       \
        _Pragma("unroll")                                                       \
        for (int nf = 0; nf < 2; ++nf) {                                        \
            int rb = wn * 32 + nf * 16 + l15;                                   \
            int cb = (ks * 64 + l4 * 16) ^ ((rb & 7) << 4);                     \
            bv[nf] = *(const bf16x8*)((const char*)Bl[CUR] + rb * 128 + cb);    \
        }                                                                       \
        _Pragma("unroll")                                                       \
        for (int mf = 0; mf < 2; ++mf)                                          \
            _Pragma("unroll")                                                   \
            for (int nf = 0; nf < 2; ++nf)                                      \
                acc[mf][nf] = __builtin_amdgcn_mfma_f32_16x16x32_bf16(          \
                    av[mf], bv[nf], acc[mf][nf], 0, 0, 0);                      \
    }

// STEP kt: stage B(kt+1), issue x tile kt+2, compute kt, write x tile kt+1.
// Staging-wave FIFO at the wait = [x_{kt+1}(2 consumed), B(4), x_{kt+2}(2)]
// -> vmcnt(2) drains B, leaves x_{kt+2}. Non-staging: [B(4)] -> vmcnt(0).
#define STEP(kt, XCa, XCb, XIa, XIb, CUR, NXT)                                  \
    {                                                                           \
        if ((kt) <= 14) STAGE_B((kt) + 1, NXT);                                 \
        __builtin_amdgcn_sched_barrier(0);                                      \
        if ((kt) <= 13 && wid < 4) {                                            \
            XIa = ((const float4*)(xrow + ((kt) + 2) * 64))[0];                 \
            XIb = ((const float4*)(xrow + ((kt) + 2) * 64))[1];                 \
        }                                                                       \
        COMPUTE(kt, CUR);                                                       \
        if ((kt) <= 14) WRITE_A(XCa, XCb, (kt) + 1);                            \
        if ((kt) <= 13) {                                                       \
            if (wid < 4) asm volatile("s_waitcnt vmcnt(2) lgkmcnt(0)" ::: "memory"); \
            else         asm volatile("s_waitcnt vmcnt(0)" ::: "memory");       \
        } else if ((kt) == 14) {                                                \
            if (wid < 4) asm volatile("s_waitcnt vmcnt(0) lgkmcnt(0)" ::: "memory"); \
            else         asm volatile("s_waitcnt vmcnt(0)" ::: "memory");       \
        }                                                                       \
        if ((kt) <= 14) {                                                       \
            __builtin_amdgcn_s_barrier();                                       \
            __builtin_amdgcn_sched_barrier(0);                                  \
        }                                                                       \
    }

    // Prologue: B0 first, then x0 (tile0), x1 (tile1) -> FIFO [B0(4), x0(2), x1(2)]
    STAGE_B(0, 0);
    __builtin_amdgcn_sched_barrier(0);
    if (wid < 4) {
        x0a = ((const float4*)(xrow))[0];
        x0b = ((const float4*)(xrow))[1];
        x1a = ((const float4*)(xrow + 64))[0];
        x1b = ((const float4*)(xrow + 64))[1];
    }
    WRITE_A(x0a, x0b, 0);   // compiler waits through x0; B0+x1 may remain
    if (wid < 4) asm volatile("s_waitcnt vmcnt(2) lgkmcnt(0)" ::: "memory");
    else         asm volatile("s_waitcnt vmcnt(0)" ::: "memory");
    __builtin_amdgcn_s_barrier();
    __builtin_amdgcn_sched_barrier(0);

    for (int kt = 0; kt < 16; kt += 2) {
        STEP(kt,     x1a, x1b, x0a, x0b, 0, 1);
        STEP(kt + 1, x0a, x0b, x1a, x1b, 1, 0);
    }
    __syncthreads();   // final drain after kt=15 compute

    // LN stats finalize (8 staging threads per row are adjacent lanes)
    if (wid < 4) {
        s  += __shfl_xor(s, 1);  s  += __shfl_xor(s, 2);  s  += __shfl_xor(s, 4);
        sq += __shfl_xor(sq, 1); sq += __shfl_xor(sq, 2); sq += __shfl_xor(sq, 4);
        if (g8 == 0) {
            float mu  = s * (1.0f / DD);
            float var = sq * (1.0f / DD) - mu * mu;
            stats[rA][0] = mu;
            stats[rA][1] = rsqrtf(var + 1e-5f);
        }
    }
    __syncthreads();

    // LN-corrected tile -> HPl (D frag: col=lane&15, row=(lane>>4)*4+i)
#pragma unroll
    for (int mf = 0; mf < 2; ++mf) {
#pragma unroll
        for (int nf = 0; nf < 2; ++nf) {
            int colg = wn * 32 + nf * 16 + l15;
            float cs = Csum_l[colg];
            float bw = Bw_l[colg];
            int r0 = mf * 16 + l4 * 4;
#pragma unroll
            for (int i = 0; i < 4; ++i) {
                float mu = stats[r0 + i][0], rs = stats[r0 + i][1];
                HPl[(r0 + i) * HPS + colg] = rs * acc[mf][nf][i] - mu * rs * cs + bw;
            }
        }
    }
    __syncthreads();

    // ---- per-row epilogue; wave w handles rows w, w+9, w+18, w+27 ----
    float4 b1v = ((const float4*)b1)[lane];
    float w2a[4], w2b[4];
#pragma unroll
    for (int i = 0; i < 4; ++i) {
        int j = lane * 4 + i;
        w2a[i] = W2[2 * j];
        w2b[i] = W2[2 * j + 1];
    }
    float tvs[2] = {0.f, 0.f};
    if (lane < NTT) {
#pragma unroll
        for (int s2 = 0; s2 < 2; ++s2) {
            float d0 = 0.f;
#pragma unroll
            for (int k = 0; k < 8; ++k) d0 += semb[s2 * 8 + k] * ssig[lane * 8 + k];
            tvs[s2] = 1.0f / (1.0f + expf(-d0));
        }
    }
    float osc = oscale[0];
    float bb0 = b2[0], bb1 = b2[1];

    for (int r = wid; r < BM; r += NW) {
        int row = row0 + r;
        float4 hv = *(const float4*)&HPl[r * HPS + lane * 4];
        float hs[4] = {hv.x, hv.y, hv.z, hv.w};
        float bs[4] = {b1v.x, b1v.y, b1v.z, b1v.w};
        float sa = 0.f, sb2 = 0.f;
#pragma unroll
        for (int i = 0; i < 4; ++i) {
            float h = hs[i] + bs[i];
            float g = 0.5f * h * (1.0f + erff(h * 0.70710678118654752f));
            sa  += g * w2a[i];
            sb2 += g * w2b[i];
        }
#pragma unroll
        for (int off = 32; off; off >>= 1) {
            sa  += __shfl_xor(sa, off);
            sb2 += __shfl_xor(sb2, off);
        }
        float av2 = tanhf(sa + bb0);
        float bv2 = tanhf(sb2 + bb1);

        int st = states[row];
        float comb;
        if (lane < NTT) {
            float content = HPl[r * HPS + HH + lane];
            float pn = positions[row] * ((float)NTT / 2048.0f);
            float spv = bspline((pn - (float)lane) * 0.5f);
            comb = content * spv * tvs[st];
        } else {
            comb = -__builtin_inff();
        }
        int bi = lane;
#pragma unroll
        for (int off = 32; off; off >>= 1) {
            float ov = __shfl_xor(comb, off);
            int   oi = __shfl_xor(bi, off);
            if (ov > comb || (ov == comb && oi < bi)) { comb = ov; bi = oi; }
        }
        int ia = (int)((av2 + 1.0f) * 8.0f); ia = ia < 0 ? 0 : (ia > 15 ? 15 : ia);
        int ib = (int)((bv2 + 1.0f) * 8.0f); ib = ib < 0 ? 0 : (ib > 15 ? 15 : ib);
        const float* cc = spc + (((size_t)bi * 16 + ia) * 16 + ib) * 3;
        float c0 = ternf(cc[0]), c1 = ternf(cc[1]), c2 = ternf(cc[2]);
        float la = (av2 + 1.0f - (float)ia * 0.125f) * 8.0f;
        float lb = (bv2 + 1.0f - (float)ib * 0.125f) * 8.0f;
        float scale = (c0 + c1 * la + c2 * lb) * sps[bi];
        float cr = scale * smod[st * NTT + bi] * osc;

        // x from LDS (bf16), dir from global; out = x + cr*dir
        int swzr = (r & 7) << 4;
        const float4* dr = (const float4*)(dirs + (size_t)bi * DD);
        float4* orow = (float4*)(out + (size_t)row * DD);
#pragma unroll
        for (int i = 0; i < 4; ++i) {
            int idx = i * 64 + lane;                  // float4 index in row
            int byteoff = r * 2048 + ((idx * 8) ^ swzr);
            ushort4 xv = *(const ushort4*)((const char*)Xl + byteoff);
            float4 dv = dr[idx];
            float4 o;
            o.x = fmaf(cr, dv.x, bf2f(xv.x));
            o.y = fmaf(cr, dv.y, bf2f(xv.y));
            o.z = fmaf(cr, dv.z, bf2f(xv.z));
            o.w = fmaf(cr, dv.w, bf2f(xv.w));
            orow[idx] = o;
        }
    }
#undef STAGE_B
#undef WRITE_A
#undef COMPUTE
#undef STEP
}

extern "C" void kernel_launch(void* const* d_in, const int* in_sizes, int n_in,
                              void* d_out, int out_size, void* d_ws, size_t ws_size,
                              hipStream_t stream) {
    const float* x     = (const float*)d_in[0];
    const float* pos   = (const float*)d_in[1];
    const int*   st    = (const int*)d_in[2];
    const float* gam   = (const float*)d_in[3];
    const float* bet   = (const float*)d_in[4];
    const float* W1    = (const float*)d_in[5];
    const float* b1    = (const float*)d_in[6];
    const float* W2    = (const float*)d_in[7];
    const float* b2    = (const float*)d_in[8];
    const float* spc   = (const float*)d_in[9];
    const float* sps   = (const float*)d_in[10];
    const float* dirs  = (const float*)d_in[11];
    const float* ssig  = (const float*)d_in[12];
    const float* semb  = (const float*)d_in[13];
    const float* smod  = (const float*)d_in[14];
    const float* oscal = (const float*)d_in[15];
    float* out = (float*)d_out;

    char* ws = (char*)d_ws;
    unsigned short* WT = (unsigned short*)ws;                  // 288*1024 bf16 = 576 KiB
    float* colsumP = (float*)(ws + 589824);                    // 32*288 f32 = 36 KiB
    float* bwP     = (float*)(ws + 589824 + 36864);            // 32*288 f32

    k_prep<<<288, 256, 0, stream>>>(W1, dirs, gam, bet, WT, colsumP, bwP);
    k_fused<<<NROWS / BM, NTHR, 0, stream>>>(x, WT, colsumP, bwP, pos, st, b1, W2, b2,
                                             spc, sps, dirs, ssig, semb, smod, oscal, out);
}